// Round 5
// baseline (301.107 us; speedup 1.0000x reference)
//
#include <hip/hip_runtime.h>

// MobileMQA: B=8, C=256, H=W=64, NUM_HEADS=4, hd=64, ds=2
// R5: attention occupancy fix — 32 q/wave, full-KV per wave, VGPR<=128 via
//     __launch_bounds__(256,4); K-only prefetch; launch_bounds on GEMMs.

#define CNT_INV (1.0f/1048576.0f)
#define EPSV 1e-5f
#define QSCALE 0.18033688f   // 0.125 * log2(e), folded into Q so exp becomes v_exp_f32(S)

// workspace layout (float offsets)
#define WS_STATS 0                    // 64
#define WS_XNT   64                   // bf16 xnT [b][n][c]  = 4,194,304 f
#define WS_XDS   4194368              // bf16 xdsT [b][m][c] = 1,048,576 f
#define WS_Q     5242944              // bf16 qT  [b][h][n][d] = 4,194,304 f
#define WS_K     9437248              // bf16 k   [b][m][d]  = 262,144 f
#define WS_V     9699392              // bf16 vT  [b][d][m]  = 262,144 f
#define WS_AOT   9961536              // bf16 aoT [b][n][c]  = 4,194,304 f
#define WS_WQB   14155840             // bf16 wq  [o][c]     = 32,768 f
#define WS_WKV   14188608             // bf16 [wk;wv]        = 16,384 f
#define WS_WOB   14204992             // bf16 wo  [o][c]     = 32,768 f

typedef __attribute__((ext_vector_type(8))) short bf8_t;   // 8 bf16 MFMA A/B frag
typedef __attribute__((ext_vector_type(4))) float f4_t;    // MFMA C/D frag

static __device__ __forceinline__ unsigned fbits(float f) {
  union { float f; unsigned u; } v; v.f = f; return v.u;
}
static __device__ __forceinline__ unsigned short f2bf(float f) {  // RNE
  unsigned u = fbits(f);
  return (unsigned short)((u + 0x7fffu + ((u >> 16) & 1u)) >> 16);
}
static __device__ __forceinline__ unsigned pk_rnd(float a, float b) {
  return __builtin_amdgcn_perm(fbits(b) + 0x8000u, fbits(a) + 0x8000u, 0x07060302u);
}
static __device__ __forceinline__ unsigned pk_tr(float a, float b) {
  return __builtin_amdgcn_perm(fbits(b), fbits(a), 0x07060302u);
}
static __device__ __forceinline__ float bf2f(unsigned short h) {
  union { unsigned u; float f; } v; v.u = ((unsigned)h) << 16; return v.f;
}
static __device__ __forceinline__ float fexp2(float x) {   // 2^x, raw v_exp_f32
  float r; asm("v_exp_f32 %0, %1" : "=v"(r) : "v"(x)); return r;
}

// ---------------- merged: weight prep (blocks >= 512) + stats (blocks < 512) ----------------
__global__ __launch_bounds__(256) void k_prep_stats(const float* __restrict__ x,
                                                    const float* __restrict__ wq,
                                                    const float* __restrict__ wk,
                                                    const float* __restrict__ wv,
                                                    const float* __restrict__ wo,
                                                    float* __restrict__ stats,
                                                    unsigned short* __restrict__ wqb,
                                                    unsigned short* __restrict__ wkvb,
                                                    unsigned short* __restrict__ wob) {
  const int blk = blockIdx.x;
  const int t = threadIdx.x;
  if (blk < 512) {
    const int b = blk >> 6;
    const int chunk = blk & 63;
    const float4* xb = (const float4*)(x + (size_t)b * 1048576 + (size_t)chunk * 16384);
    float s = 0.f, s2 = 0.f;
#pragma unroll
    for (int it = 0; it < 16; ++it) {
      float4 v = xb[it * 256 + t];
      s  += v.x + v.y + v.z + v.w;
      s2 += v.x * v.x + v.y * v.y + v.z * v.z + v.w * v.w;
    }
#pragma unroll
    for (int o = 32; o > 0; o >>= 1) {
      s  += __shfl_down(s, o);
      s2 += __shfl_down(s2, o);
    }
    __shared__ float red[8];
    const int wid = t >> 6;
    if ((t & 63) == 0) { red[wid] = s; red[4 + wid] = s2; }
    __syncthreads();
    if (t == 0) {
      atomicAdd(&stats[b * 2 + 0], red[0] + red[1] + red[2] + red[3]);
      atomicAdd(&stats[b * 2 + 1], red[4] + red[5] + red[6] + red[7]);
    }
  } else {
    const int idx = (blk - 512) * 256 + t;
    if (idx < 65536) wqb[idx] = f2bf(wq[idx]);
    else if (idx < 81920) wkvb[idx - 65536] = f2bf(wk[idx - 65536]);
    else if (idx < 98304) wkvb[idx - 65536] = f2bf(wv[idx - 81920]);
    else if (idx < 163840) wob[idx - 98304] = f2bf(wo[idx - 98304]);
  }
}

// ---------------- normalize + transpose + fused 2x2 pool ----------------
__global__ __launch_bounds__(256) void k_xnt(const float* __restrict__ x,
                                             const float* __restrict__ gnw,
                                             const float* __restrict__ gnb,
                                             const float* __restrict__ stats,
                                             unsigned short* __restrict__ xnT,
                                             unsigned short* __restrict__ xdsT) {
  __shared__ unsigned short T[128][72];   // [n_local][c_local]
  const int t = threadIdx.x;
  const int b = blockIdx.z, c0 = blockIdx.y * 64, hp = blockIdx.x;
  const int n0 = hp * 128;
  const float mu = stats[b * 2 + 0] * CNT_INV;
  const float rstd = rsqrtf(stats[b * 2 + 1] * CNT_INV - mu * mu + EPSV);
  const int n4 = (t & 31) * 4, cl = t >> 5;
#pragma unroll
  for (int p = 0; p < 8; ++p) {
    const int c = c0 + p * 8 + cl;
    const float gw = gnw[c] * rstd;
    const float gb = gnb[c] - mu * rstd * gnw[c];
    float4 v = *(const float4*)&x[(size_t)(b * 256 + c) * 4096 + n0 + n4];
    T[n4 + 0][p * 8 + cl] = f2bf(v.x * gw + gb);
    T[n4 + 1][p * 8 + cl] = f2bf(v.y * gw + gb);
    T[n4 + 2][p * 8 + cl] = f2bf(v.z * gw + gb);
    T[n4 + 3][p * 8 + cl] = f2bf(v.w * gw + gb);
  }
  __syncthreads();
  {  // write xnT: 128 rows x 64 c
    const int r = t >> 1, ch = (t & 1) * 32;
    unsigned short* dst = xnT + ((size_t)b * 4096 + n0 + r) * 256 + c0 + ch;
#pragma unroll
    for (int u = 0; u < 4; ++u)
      *(uint4*)(dst + u * 8) = *(const uint4*)&T[r][ch + u * 8];
  }
  {  // fused pool: 32 m x 64 c
    const int wd = t & 31, c8 = (t >> 5) * 8;
    uint4 u0 = *(const uint4*)&T[2 * wd][c8];
    uint4 u1 = *(const uint4*)&T[2 * wd + 1][c8];
    uint4 u2 = *(const uint4*)&T[64 + 2 * wd][c8];
    uint4 u3 = *(const uint4*)&T[64 + 2 * wd + 1][c8];
    const unsigned* p0 = (const unsigned*)&u0; const unsigned* p1 = (const unsigned*)&u1;
    const unsigned* p2 = (const unsigned*)&u2; const unsigned* p3 = (const unsigned*)&u3;
    unsigned outp[4];
#pragma unroll
    for (int i = 0; i < 4; ++i) {
      float lo = (bf2f((unsigned short)p0[i]) + bf2f((unsigned short)p1[i]) +
                  bf2f((unsigned short)p2[i]) + bf2f((unsigned short)p3[i])) * 0.25f;
      float hi = (bf2f((unsigned short)(p0[i] >> 16)) + bf2f((unsigned short)(p1[i] >> 16)) +
                  bf2f((unsigned short)(p2[i] >> 16)) + bf2f((unsigned short)(p3[i] >> 16))) * 0.25f;
      outp[i] = pk_rnd(lo, hi);
    }
    *(uint4*)(xdsT + ((size_t)b * 1024 + hp * 32 + wd) * 256 + c0 + c8) = *(uint4*)outp;
  }
}

// ---------------- Q gemm (MFMA, staging-free): qT bf16, scaled by 0.125*log2e ----------------
__global__ __launch_bounds__(256, 4) void k_gemm_q(const unsigned short* __restrict__ wqb,
                                                   const unsigned short* __restrict__ xnT,
                                                   unsigned short* __restrict__ qbf) {
  const int t = threadIdx.x;
  const int h = t >> 6, l = t & 63, lane16 = l & 15, quad = l >> 4;
  const int n0 = blockIdx.x * 64, b = blockIdx.y;
  f4_t acc[4][4];
#pragma unroll
  for (int i = 0; i < 4; ++i)
#pragma unroll
    for (int j = 0; j < 4; ++j) acc[i][j] = (f4_t){0.f, 0.f, 0.f, 0.f};
  for (int kc = 0; kc < 256; kc += 32) {
    bf8_t A[4], Bf[4];
#pragma unroll
    for (int og = 0; og < 4; ++og)
      A[og] = *(const bf8_t*)(wqb + (size_t)(h * 64 + og * 16 + lane16) * 256 + kc + quad * 8);
#pragma unroll
    for (int ng = 0; ng < 4; ++ng)
      Bf[ng] = *(const bf8_t*)(xnT + ((size_t)b * 4096 + n0 + ng * 16 + lane16) * 256 + kc + quad * 8);
#pragma unroll
    for (int og = 0; og < 4; ++og)
#pragma unroll
      for (int ng = 0; ng < 4; ++ng)
        acc[og][ng] = __builtin_amdgcn_mfma_f32_16x16x32_bf16(A[og], Bf[ng], acc[og][ng], 0, 0, 0);
  }
#pragma unroll
  for (int og = 0; og < 4; ++og)
#pragma unroll
    for (int ng = 0; ng < 4; ++ng) {
      const int n = n0 + ng * 16 + lane16;
      uint2 p;
      p.x = pk_rnd(acc[og][ng][0] * QSCALE, acc[og][ng][1] * QSCALE);
      p.y = pk_rnd(acc[og][ng][2] * QSCALE, acc[og][ng][3] * QSCALE);
      *(uint2*)(qbf + ((size_t)(b * 4 + h) * 4096 + n) * 64 + og * 16 + quad * 4) = p;
    }
}

// ---------------- K/V gemm (MFMA): k[b][m][d], vT[b][d][m] bf16 ----------------
__global__ __launch_bounds__(256) void k_gemm_kv(const unsigned short* __restrict__ wkvb,
                                                 const unsigned short* __restrict__ xdsT,
                                                 unsigned short* __restrict__ kbf,
                                                 unsigned short* __restrict__ vtbf) {
  const int t = threadIdx.x;
  const int w = t >> 6, l = t & 63, lane16 = l & 15, quad = l >> 4;
  const int m0 = blockIdx.x * 64, b = blockIdx.y;
  f4_t acc[2][4];
#pragma unroll
  for (int i = 0; i < 2; ++i)
#pragma unroll
    for (int j = 0; j < 4; ++j) acc[i][j] = (f4_t){0.f, 0.f, 0.f, 0.f};
  for (int kc = 0; kc < 256; kc += 32) {
    bf8_t A[2], Bf[4];
#pragma unroll
    for (int og = 0; og < 2; ++og)
      A[og] = *(const bf8_t*)(wkvb + (size_t)(w * 32 + og * 16 + lane16) * 256 + kc + quad * 8);
#pragma unroll
    for (int mg = 0; mg < 4; ++mg)
      Bf[mg] = *(const bf8_t*)(xdsT + ((size_t)b * 1024 + m0 + mg * 16 + lane16) * 256 + kc + quad * 8);
#pragma unroll
    for (int og = 0; og < 2; ++og)
#pragma unroll
      for (int mg = 0; mg < 4; ++mg)
        acc[og][mg] = __builtin_amdgcn_mfma_f32_16x16x32_bf16(A[og], Bf[mg], acc[og][mg], 0, 0, 0);
  }
  if (w < 2) {  // K -> kbf[m][d]
#pragma unroll
    for (int og = 0; og < 2; ++og)
#pragma unroll
      for (int mg = 0; mg < 4; ++mg) {
        const int m = m0 + mg * 16 + lane16;
        uint2 p;
        p.x = pk_rnd(acc[og][mg][0], acc[og][mg][1]);
        p.y = pk_rnd(acc[og][mg][2], acc[og][mg][3]);
        *(uint2*)(kbf + (size_t)b * 65536 + (size_t)m * 64 + w * 32 + og * 16 + quad * 4) = p;
      }
  } else {  // V -> vT[d][m]
#pragma unroll
    for (int og = 0; og < 2; ++og)
#pragma unroll
      for (int mg = 0; mg < 4; ++mg) {
        const int m = m0 + mg * 16 + lane16;
        const int d0 = (w - 2) * 32 + og * 16 + quad * 4;
#pragma unroll
        for (int r = 0; r < 4; ++r)
          vtbf[(size_t)b * 65536 + (size_t)(d0 + r) * 1024 + m] = f2bf(acc[og][mg][r]);
      }
  }
}

// ---------------- MFMA attention: 32 q/wave, full KV, 4 waves/SIMD ----------------
__global__ __launch_bounds__(256, 4) void k_attn_mfma(const unsigned short* __restrict__ qbf,
                                                      const unsigned short* __restrict__ kbf,
                                                      const unsigned short* __restrict__ vtbf,
                                                      unsigned short* __restrict__ aoT) {
  __shared__ __align__(16) unsigned short plds[4][32][36];  // per-wave P stage [q][kv]
  const int t = threadIdx.x;
  const int w = t >> 6, l = t & 63, lane16 = l & 15, quad = l >> 4;
  const int h = blockIdx.y, b = blockIdx.z;
  const int q0 = blockIdx.x * 128 + w * 32;

  const unsigned short* qb = qbf + ((size_t)(b * 4 + h) * 4096 + q0) * 64;
  const unsigned short* kb = kbf + (size_t)b * 65536;
  const unsigned short* vb = vtbf + (size_t)b * 65536;

  bf8_t Qf[2][2];
#pragma unroll
  for (int qg = 0; qg < 2; ++qg)
#pragma unroll
    for (int dc = 0; dc < 2; ++dc)
      Qf[qg][dc] = *(const bf8_t*)(qb + (qg * 16 + lane16) * 64 + dc * 32 + quad * 8);

  f4_t O[4][2];
#pragma unroll
  for (int dg = 0; dg < 4; ++dg)
#pragma unroll
    for (int qg = 0; qg < 2; ++qg) O[dg][qg] = (f4_t){0.f, 0.f, 0.f, 0.f};
  float den[2] = {0.f, 0.f};

  bf8_t Kc[2][2];
#pragma unroll
  for (int s = 0; s < 2; ++s)
#pragma unroll
    for (int dc = 0; dc < 2; ++dc)
      Kc[s][dc] = *(const bf8_t*)(kb + (size_t)(s * 16 + lane16) * 64 + dc * 32 + quad * 8);

  for (int it = 0; it < 32; ++it) {
    const int kv0 = it * 32;
    // V for current iter: issue early, consumed after the S/exp phase
    bf8_t Vc[4];
#pragma unroll
    for (int dg = 0; dg < 4; ++dg)
      Vc[dg] = *(const bf8_t*)(vb + (size_t)(dg * 16 + lane16) * 1024 + kv0 + quad * 8);
    // K prefetch for next iter
    const int kvn = (kv0 + 32) & 1023;
    bf8_t Kn[2][2];
#pragma unroll
    for (int s = 0; s < 2; ++s)
#pragma unroll
      for (int dc = 0; dc < 2; ++dc)
        Kn[s][dc] = *(const bf8_t*)(kb + (size_t)(kvn + s * 16 + lane16) * 64 + dc * 32 + quad * 8);

#pragma unroll
    for (int qg = 0; qg < 2; ++qg)
#pragma unroll
      for (int s = 0; s < 2; ++s) {
        f4_t S = (f4_t){0.f, 0.f, 0.f, 0.f};
        S = __builtin_amdgcn_mfma_f32_16x16x32_bf16(Kc[s][0], Qf[qg][0], S, 0, 0, 0);
        S = __builtin_amdgcn_mfma_f32_16x16x32_bf16(Kc[s][1], Qf[qg][1], S, 0, 0, 0);
        float e0 = fexp2(S[0]);
        float e1 = fexp2(S[1]);
        float e2 = fexp2(S[2]);
        float e3 = fexp2(S[3]);
        den[qg] += (e0 + e1) + (e2 + e3);
        uint2 p; p.x = pk_tr(e0, e1); p.y = pk_tr(e2, e3);
        *(uint2*)&plds[w][qg * 16 + lane16][s * 16 + quad * 4] = p;
      }

    bf8_t Pf[2];
#pragma unroll
    for (int qg = 0; qg < 2; ++qg)
      Pf[qg] = *(const bf8_t*)&plds[w][qg * 16 + lane16][quad * 8];
#pragma unroll
    for (int dg = 0; dg < 4; ++dg)
#pragma unroll
      for (int qg = 0; qg < 2; ++qg)
        O[dg][qg] = __builtin_amdgcn_mfma_f32_16x16x32_bf16(Vc[dg], Pf[qg], O[dg][qg], 0, 0, 0);

#pragma unroll
    for (int s = 0; s < 2; ++s)
#pragma unroll
      for (int dc = 0; dc < 2; ++dc) Kc[s][dc] = Kn[s][dc];
  }

  float rden[2];
#pragma unroll
  for (int qg = 0; qg < 2; ++qg) {
    float d = den[qg];
    d += __shfl_xor(d, 16);
    d += __shfl_xor(d, 32);
    rden[qg] = 1.f / d;
  }

#pragma unroll
  for (int dg = 0; dg < 4; ++dg)
#pragma unroll
    for (int qg = 0; qg < 2; ++qg) {
      const int c0 = h * 64 + dg * 16 + quad * 4;
      const int n = q0 + qg * 16 + lane16;
      uint2 p;
      p.x = pk_rnd(O[dg][qg][0] * rden[qg], O[dg][qg][1] * rden[qg]);
      p.y = pk_rnd(O[dg][qg][2] * rden[qg], O[dg][qg][3] * rden[qg]);
      *(uint2*)(aoT + ((size_t)b * 4096 + n) * 256 + c0) = p;
    }
}

// ---------------- WO gemm (MFMA, staging-free) + residual ----------------
__global__ __launch_bounds__(256, 4) void k_gemm_wo(const unsigned short* __restrict__ wob,
                                                    const unsigned short* __restrict__ aoT,
                                                    const float* __restrict__ x,
                                                    const float* __restrict__ gamma,
                                                    float* __restrict__ outp) {
  const int t = threadIdx.x;
  const int w = t >> 6, l = t & 63, lane16 = l & 15, quad = l >> 4;
  const int n0 = blockIdx.x * 64, b = blockIdx.y;
  f4_t acc[4][4];
#pragma unroll
  for (int i = 0; i < 4; ++i)
#pragma unroll
    for (int j = 0; j < 4; ++j) acc[i][j] = (f4_t){0.f, 0.f, 0.f, 0.f};
  for (int kc = 0; kc < 256; kc += 32) {
    bf8_t A[4], Bf[4];
#pragma unroll
    for (int og = 0; og < 4; ++og)
      A[og] = *(const bf8_t*)(wob + (size_t)(w * 64 + og * 16 + lane16) * 256 + kc + quad * 8);
#pragma unroll
    for (int ng = 0; ng < 4; ++ng)
      Bf[ng] = *(const bf8_t*)(aoT + ((size_t)b * 4096 + n0 + ng * 16 + lane16) * 256 + kc + quad * 8);
#pragma unroll
    for (int og = 0; og < 4; ++og)
#pragma unroll
      for (int ng = 0; ng < 4; ++ng)
        acc[og][ng] = __builtin_amdgcn_mfma_f32_16x16x32_bf16(A[og], Bf[ng], acc[og][ng], 0, 0, 0);
  }
#pragma unroll
  for (int og = 0; og < 4; ++og) {
    float4 g4 = *(const float4*)&gamma[w * 64 + og * 16 + quad * 4];
    const float g[4] = {g4.x, g4.y, g4.z, g4.w};
#pragma unroll
    for (int ng = 0; ng < 4; ++ng) {
      const int n = n0 + ng * 16 + lane16;
#pragma unroll
      for (int r = 0; r < 4; ++r) {
        const int o = w * 64 + og * 16 + quad * 4 + r;
        const size_t ix = ((size_t)(b * 256 + o)) * 4096 + n;
        outp[ix] = x[ix] + g[r] * acc[og][ng][r];
      }
    }
  }
}

extern "C" void kernel_launch(void* const* d_in, const int* in_sizes, int n_in,
                              void* d_out, int out_size, void* d_ws, size_t ws_size,
                              hipStream_t stream) {
  const float* x     = (const float*)d_in[0];
  const float* gnw   = (const float*)d_in[1];
  const float* gnb   = (const float*)d_in[2];
  const float* wq    = (const float*)d_in[3];
  const float* wk    = (const float*)d_in[4];
  const float* wv    = (const float*)d_in[5];
  const float* wo    = (const float*)d_in[6];
  const float* gamma = (const float*)d_in[7];
  float* out = (float*)d_out;
  float* ws  = (float*)d_ws;
  unsigned short* xnT  = (unsigned short*)(ws + WS_XNT);
  unsigned short* xdsT = (unsigned short*)(ws + WS_XDS);
  unsigned short* qbf  = (unsigned short*)(ws + WS_Q);
  unsigned short* kbf  = (unsigned short*)(ws + WS_K);
  unsigned short* vtbf = (unsigned short*)(ws + WS_V);
  unsigned short* aoT  = (unsigned short*)(ws + WS_AOT);
  unsigned short* wqb  = (unsigned short*)(ws + WS_WQB);
  unsigned short* wkvb = (unsigned short*)(ws + WS_WKV);
  unsigned short* wob  = (unsigned short*)(ws + WS_WOB);

  hipMemsetAsync(ws, 0, 256, stream);
  k_prep_stats<<<1152, 256, 0, stream>>>(x, wq, wk, wv, wo, ws + WS_STATS, wqb, wkvb, wob);
  k_xnt<<<dim3(32, 4, 8), 256, 0, stream>>>(x, gnw, gnb, ws + WS_STATS, xnT, xdsT);
  k_gemm_q<<<dim3(64, 8), 256, 0, stream>>>(wqb, xnT, qbf);
  k_gemm_kv<<<dim3(16, 8), 256, 0, stream>>>(wkvb, xdsT, kbf, vtbf);
  k_attn_mfma<<<dim3(32, 4, 8), 256, 0, stream>>>(qbf, kbf, vtbf, aoT);
  k_gemm_wo<<<dim3(64, 8), 256, 0, stream>>>(wob, aoT, x, gamma, out);
}

// Round 6
// 232.680 us; speedup vs baseline: 1.2941x; 1.2941x over previous
//
#include <hip/hip_runtime.h>

// MobileMQA: B=8, C=256, H=W=64, NUM_HEADS=4, hd=64, ds=2
// R6: attention software-pipelined (PV lags S by one KV step, double-buffered
//     per-wave P stage) + K-prefetch in all projection GEMMs.

#define CNT_INV (1.0f/1048576.0f)
#define EPSV 1e-5f
#define QSCALE 0.18033688f   // 0.125 * log2(e): folded into Q; exp becomes v_exp_f32(S)

// workspace layout (float offsets)
#define WS_STATS 0                    // 64
#define WS_XNT   64                   // bf16 xnT [b][n][c]  = 4,194,304 f
#define WS_XDS   4194368              // bf16 xdsT [b][m][c] = 1,048,576 f
#define WS_Q     5242944              // bf16 qT  [b][h][n][d] = 4,194,304 f
#define WS_K     9437248              // bf16 k   [b][m][d]  = 262,144 f
#define WS_V     9699392              // bf16 vT  [b][d][m]  = 262,144 f
#define WS_AOT   9961536              // bf16 aoT [b][n][c]  = 4,194,304 f
#define WS_WQB   14155840             // bf16 wq  [o][c]     = 32,768 f
#define WS_WKV   14188608             // bf16 [wk;wv]        = 16,384 f
#define WS_WOB   14204992             // bf16 wo  [o][c]     = 32,768 f

typedef __attribute__((ext_vector_type(8))) short bf8_t;   // 8 bf16 MFMA A/B frag
typedef __attribute__((ext_vector_type(4))) float f4_t;    // MFMA C/D frag

static __device__ __forceinline__ unsigned fbits(float f) {
  union { float f; unsigned u; } v; v.f = f; return v.u;
}
static __device__ __forceinline__ unsigned short f2bf(float f) {  // RNE
  unsigned u = fbits(f);
  return (unsigned short)((u + 0x7fffu + ((u >> 16) & 1u)) >> 16);
}
static __device__ __forceinline__ unsigned pk_rnd(float a, float b) {
  return __builtin_amdgcn_perm(fbits(b) + 0x8000u, fbits(a) + 0x8000u, 0x07060302u);
}
static __device__ __forceinline__ unsigned pk_tr(float a, float b) {
  return __builtin_amdgcn_perm(fbits(b), fbits(a), 0x07060302u);
}
static __device__ __forceinline__ float bf2f(unsigned short h) {
  union { unsigned u; float f; } v; v.u = ((unsigned)h) << 16; return v.f;
}
static __device__ __forceinline__ float fexp2(float x) {   // 2^x, raw v_exp_f32
  float r; asm("v_exp_f32 %0, %1" : "=v"(r) : "v"(x)); return r;
}

// ---------------- merged: weight prep (blocks >= 512) + stats (blocks < 512) ----------------
__global__ __launch_bounds__(256) void k_prep_stats(const float* __restrict__ x,
                                                    const float* __restrict__ wq,
                                                    const float* __restrict__ wk,
                                                    const float* __restrict__ wv,
                                                    const float* __restrict__ wo,
                                                    float* __restrict__ stats,
                                                    unsigned short* __restrict__ wqb,
                                                    unsigned short* __restrict__ wkvb,
                                                    unsigned short* __restrict__ wob) {
  const int blk = blockIdx.x;
  const int t = threadIdx.x;
  if (blk < 512) {
    const int b = blk >> 6;
    const int chunk = blk & 63;
    const float4* xb = (const float4*)(x + (size_t)b * 1048576 + (size_t)chunk * 16384);
    float s = 0.f, s2 = 0.f;
#pragma unroll
    for (int it = 0; it < 16; ++it) {
      float4 v = xb[it * 256 + t];
      s  += v.x + v.y + v.z + v.w;
      s2 += v.x * v.x + v.y * v.y + v.z * v.z + v.w * v.w;
    }
#pragma unroll
    for (int o = 32; o > 0; o >>= 1) {
      s  += __shfl_down(s, o);
      s2 += __shfl_down(s2, o);
    }
    __shared__ float red[8];
    const int wid = t >> 6;
    if ((t & 63) == 0) { red[wid] = s; red[4 + wid] = s2; }
    __syncthreads();
    if (t == 0) {
      atomicAdd(&stats[b * 2 + 0], red[0] + red[1] + red[2] + red[3]);
      atomicAdd(&stats[b * 2 + 1], red[4] + red[5] + red[6] + red[7]);
    }
  } else {
    const int idx = (blk - 512) * 256 + t;
    if (idx < 65536) wqb[idx] = f2bf(wq[idx]);
    else if (idx < 81920) wkvb[idx - 65536] = f2bf(wk[idx - 65536]);
    else if (idx < 98304) wkvb[idx - 65536] = f2bf(wv[idx - 81920]);
    else if (idx < 163840) wob[idx - 98304] = f2bf(wo[idx - 98304]);
  }
}

// ---------------- normalize + transpose + fused 2x2 pool ----------------
__global__ __launch_bounds__(256) void k_xnt(const float* __restrict__ x,
                                             const float* __restrict__ gnw,
                                             const float* __restrict__ gnb,
                                             const float* __restrict__ stats,
                                             unsigned short* __restrict__ xnT,
                                             unsigned short* __restrict__ xdsT) {
  __shared__ unsigned short T[128][72];   // [n_local][c_local]
  const int t = threadIdx.x;
  const int b = blockIdx.z, c0 = blockIdx.y * 64, hp = blockIdx.x;
  const int n0 = hp * 128;
  const float mu = stats[b * 2 + 0] * CNT_INV;
  const float rstd = rsqrtf(stats[b * 2 + 1] * CNT_INV - mu * mu + EPSV);
  const int n4 = (t & 31) * 4, cl = t >> 5;
#pragma unroll
  for (int p = 0; p < 8; ++p) {
    const int c = c0 + p * 8 + cl;
    const float gw = gnw[c] * rstd;
    const float gb = gnb[c] - mu * rstd * gnw[c];
    float4 v = *(const float4*)&x[(size_t)(b * 256 + c) * 4096 + n0 + n4];
    T[n4 + 0][p * 8 + cl] = f2bf(v.x * gw + gb);
    T[n4 + 1][p * 8 + cl] = f2bf(v.y * gw + gb);
    T[n4 + 2][p * 8 + cl] = f2bf(v.z * gw + gb);
    T[n4 + 3][p * 8 + cl] = f2bf(v.w * gw + gb);
  }
  __syncthreads();
  {  // write xnT: 128 rows x 64 c
    const int r = t >> 1, ch = (t & 1) * 32;
    unsigned short* dst = xnT + ((size_t)b * 4096 + n0 + r) * 256 + c0 + ch;
#pragma unroll
    for (int u = 0; u < 4; ++u)
      *(uint4*)(dst + u * 8) = *(const uint4*)&T[r][ch + u * 8];
  }
  {  // fused pool: 32 m x 64 c
    const int wd = t & 31, c8 = (t >> 5) * 8;
    uint4 u0 = *(const uint4*)&T[2 * wd][c8];
    uint4 u1 = *(const uint4*)&T[2 * wd + 1][c8];
    uint4 u2 = *(const uint4*)&T[64 + 2 * wd][c8];
    uint4 u3 = *(const uint4*)&T[64 + 2 * wd + 1][c8];
    const unsigned* p0 = (const unsigned*)&u0; const unsigned* p1 = (const unsigned*)&u1;
    const unsigned* p2 = (const unsigned*)&u2; const unsigned* p3 = (const unsigned*)&u3;
    unsigned outp[4];
#pragma unroll
    for (int i = 0; i < 4; ++i) {
      float lo = (bf2f((unsigned short)p0[i]) + bf2f((unsigned short)p1[i]) +
                  bf2f((unsigned short)p2[i]) + bf2f((unsigned short)p3[i])) * 0.25f;
      float hi = (bf2f((unsigned short)(p0[i] >> 16)) + bf2f((unsigned short)(p1[i] >> 16)) +
                  bf2f((unsigned short)(p2[i] >> 16)) + bf2f((unsigned short)(p3[i] >> 16))) * 0.25f;
      outp[i] = pk_rnd(lo, hi);
    }
    *(uint4*)(xdsT + ((size_t)b * 1024 + hp * 32 + wd) * 256 + c0 + c8) = *(uint4*)outp;
  }
}

// ---------------- Q gemm (MFMA, staging-free, K-prefetch): qT bf16 * QSCALE ----------------
__global__ __launch_bounds__(256) void k_gemm_q(const unsigned short* __restrict__ wqb,
                                                const unsigned short* __restrict__ xnT,
                                                unsigned short* __restrict__ qbf) {
  const int t = threadIdx.x;
  const int h = t >> 6, l = t & 63, lane16 = l & 15, quad = l >> 4;
  const int n0 = blockIdx.x * 64, b = blockIdx.y;
  const unsigned short* Abase = wqb + (size_t)(h * 64 + lane16) * 256 + quad * 8;
  const unsigned short* Bbase = xnT + ((size_t)b * 4096 + n0 + lane16) * 256 + quad * 8;
  f4_t acc[4][4];
#pragma unroll
  for (int i = 0; i < 4; ++i)
#pragma unroll
    for (int j = 0; j < 4; ++j) acc[i][j] = (f4_t){0.f, 0.f, 0.f, 0.f};
  bf8_t Ac[4], Bc[4];
#pragma unroll
  for (int og = 0; og < 4; ++og) Ac[og] = *(const bf8_t*)(Abase + (size_t)og * 16 * 256);
#pragma unroll
  for (int ng = 0; ng < 4; ++ng) Bc[ng] = *(const bf8_t*)(Bbase + (size_t)ng * 16 * 256);
  for (int kc = 0; kc < 256; kc += 32) {
    const int kn = (kc + 32) & 255;
    bf8_t An[4], Bn[4];
#pragma unroll
    for (int og = 0; og < 4; ++og) An[og] = *(const bf8_t*)(Abase + (size_t)og * 16 * 256 + kn);
#pragma unroll
    for (int ng = 0; ng < 4; ++ng) Bn[ng] = *(const bf8_t*)(Bbase + (size_t)ng * 16 * 256 + kn);
#pragma unroll
    for (int og = 0; og < 4; ++og)
#pragma unroll
      for (int ng = 0; ng < 4; ++ng)
        acc[og][ng] = __builtin_amdgcn_mfma_f32_16x16x32_bf16(Ac[og], Bc[ng], acc[og][ng], 0, 0, 0);
#pragma unroll
    for (int og = 0; og < 4; ++og) Ac[og] = An[og];
#pragma unroll
    for (int ng = 0; ng < 4; ++ng) Bc[ng] = Bn[ng];
  }
#pragma unroll
  for (int og = 0; og < 4; ++og)
#pragma unroll
    for (int ng = 0; ng < 4; ++ng) {
      const int n = n0 + ng * 16 + lane16;
      uint2 p;
      p.x = pk_rnd(acc[og][ng][0] * QSCALE, acc[og][ng][1] * QSCALE);
      p.y = pk_rnd(acc[og][ng][2] * QSCALE, acc[og][ng][3] * QSCALE);
      *(uint2*)(qbf + ((size_t)(b * 4 + h) * 4096 + n) * 64 + og * 16 + quad * 4) = p;
    }
}

// ---------------- K/V gemm (MFMA, K-prefetch): k[b][m][d], vT[b][d][m] bf16 ----------------
__global__ __launch_bounds__(256) void k_gemm_kv(const unsigned short* __restrict__ wkvb,
                                                 const unsigned short* __restrict__ xdsT,
                                                 unsigned short* __restrict__ kbf,
                                                 unsigned short* __restrict__ vtbf) {
  const int t = threadIdx.x;
  const int w = t >> 6, l = t & 63, lane16 = l & 15, quad = l >> 4;
  const int m0 = blockIdx.x * 64, b = blockIdx.y;
  const unsigned short* Abase = wkvb + (size_t)(w * 32 + lane16) * 256 + quad * 8;
  const unsigned short* Bbase = xdsT + ((size_t)b * 1024 + m0 + lane16) * 256 + quad * 8;
  f4_t acc[2][4];
#pragma unroll
  for (int i = 0; i < 2; ++i)
#pragma unroll
    for (int j = 0; j < 4; ++j) acc[i][j] = (f4_t){0.f, 0.f, 0.f, 0.f};
  bf8_t Ac[2], Bc[4];
#pragma unroll
  for (int og = 0; og < 2; ++og) Ac[og] = *(const bf8_t*)(Abase + (size_t)og * 16 * 256);
#pragma unroll
  for (int mg = 0; mg < 4; ++mg) Bc[mg] = *(const bf8_t*)(Bbase + (size_t)mg * 16 * 256);
  for (int kc = 0; kc < 256; kc += 32) {
    const int kn = (kc + 32) & 255;
    bf8_t An[2], Bn[4];
#pragma unroll
    for (int og = 0; og < 2; ++og) An[og] = *(const bf8_t*)(Abase + (size_t)og * 16 * 256 + kn);
#pragma unroll
    for (int mg = 0; mg < 4; ++mg) Bn[mg] = *(const bf8_t*)(Bbase + (size_t)mg * 16 * 256 + kn);
#pragma unroll
    for (int og = 0; og < 2; ++og)
#pragma unroll
      for (int mg = 0; mg < 4; ++mg)
        acc[og][mg] = __builtin_amdgcn_mfma_f32_16x16x32_bf16(Ac[og], Bc[mg], acc[og][mg], 0, 0, 0);
#pragma unroll
    for (int og = 0; og < 2; ++og) Ac[og] = An[og];
#pragma unroll
    for (int mg = 0; mg < 4; ++mg) Bc[mg] = Bn[mg];
  }
  if (w < 2) {  // K -> kbf[m][d]
#pragma unroll
    for (int og = 0; og < 2; ++og)
#pragma unroll
      for (int mg = 0; mg < 4; ++mg) {
        const int m = m0 + mg * 16 + lane16;
        uint2 p;
        p.x = pk_rnd(acc[og][mg][0], acc[og][mg][1]);
        p.y = pk_rnd(acc[og][mg][2], acc[og][mg][3]);
        *(uint2*)(kbf + (size_t)b * 65536 + (size_t)m * 64 + w * 32 + og * 16 + quad * 4) = p;
      }
  } else {  // V -> vT[d][m]
#pragma unroll
    for (int og = 0; og < 2; ++og)
#pragma unroll
      for (int mg = 0; mg < 4; ++mg) {
        const int m = m0 + mg * 16 + lane16;
        const int d0 = (w - 2) * 32 + og * 16 + quad * 4;
#pragma unroll
        for (int r = 0; r < 4; ++r)
          vtbf[(size_t)b * 65536 + (size_t)(d0 + r) * 1024 + m] = f2bf(acc[og][mg][r]);
      }
  }
}

// ---------------- MFMA attention: 64 q/wave, software-pipelined P (PV lags S) ----------------
__global__ __launch_bounds__(128) void k_attn_mfma(const unsigned short* __restrict__ qbf,
                                                   const unsigned short* __restrict__ kbf,
                                                   const unsigned short* __restrict__ vtbf,
                                                   unsigned short* __restrict__ aoT) {
  __shared__ __align__(16) unsigned short plds[2][2][64][36];  // [wave][buf][q][kv]
  const int t = threadIdx.x;
  const int w = t >> 6, l = t & 63, lane16 = l & 15, quad = l >> 4;
  const int h = blockIdx.y, b = blockIdx.z;
  const int q0 = blockIdx.x * 128 + w * 64;

  const unsigned short* qb = qbf + ((size_t)(b * 4 + h) * 4096 + q0) * 64;
  const unsigned short* kb = kbf + (size_t)b * 65536;
  const unsigned short* vb = vtbf + (size_t)b * 65536;

  bf8_t Qf[4][2];
#pragma unroll
  for (int qg = 0; qg < 4; ++qg)
#pragma unroll
    for (int dc = 0; dc < 2; ++dc)
      Qf[qg][dc] = *(const bf8_t*)(qb + (qg * 16 + lane16) * 64 + dc * 32 + quad * 8);

  f4_t O[4][4];
#pragma unroll
  for (int dg = 0; dg < 4; ++dg)
#pragma unroll
    for (int qg = 0; qg < 4; ++qg) O[dg][qg] = (f4_t){0.f, 0.f, 0.f, 0.f};
  float den[4] = {0.f, 0.f, 0.f, 0.f};

#define SSTEP(KREG, BUF)                                                      \
  {                                                                           \
    _Pragma("unroll")                                                         \
    for (int qg = 0; qg < 4; ++qg) {                                          \
      _Pragma("unroll")                                                       \
      for (int s = 0; s < 2; ++s) {                                           \
        f4_t S = (f4_t){0.f, 0.f, 0.f, 0.f};                                  \
        S = __builtin_amdgcn_mfma_f32_16x16x32_bf16(KREG[s][0], Qf[qg][0], S, 0, 0, 0); \
        S = __builtin_amdgcn_mfma_f32_16x16x32_bf16(KREG[s][1], Qf[qg][1], S, 0, 0, 0); \
        float e0 = fexp2(S[0]);                                               \
        float e1 = fexp2(S[1]);                                               \
        float e2 = fexp2(S[2]);                                               \
        float e3 = fexp2(S[3]);                                               \
        den[qg] += (e0 + e1) + (e2 + e3);                                     \
        uint2 p; p.x = pk_tr(e0, e1); p.y = pk_tr(e2, e3);                    \
        *(uint2*)&plds[w][BUF][qg * 16 + lane16][s * 16 + quad * 4] = p;      \
      }                                                                       \
    }                                                                         \
  }

  // prologue: K(0) -> S(0) -> buf 0
  bf8_t Kc[2][2];
#pragma unroll
  for (int s = 0; s < 2; ++s)
#pragma unroll
    for (int dc = 0; dc < 2; ++dc)
      Kc[s][dc] = *(const bf8_t*)(kb + (size_t)(s * 16 + lane16) * 64 + dc * 32 + quad * 8);
  SSTEP(Kc, 0);

  // preload K(1), V(0)
  bf8_t Vc[4];
#pragma unroll
  for (int s = 0; s < 2; ++s)
#pragma unroll
    for (int dc = 0; dc < 2; ++dc)
      Kc[s][dc] = *(const bf8_t*)(kb + (size_t)(32 + s * 16 + lane16) * 64 + dc * 32 + quad * 8);
#pragma unroll
  for (int dg = 0; dg < 4; ++dg)
    Vc[dg] = *(const bf8_t*)(vb + (size_t)(dg * 16 + lane16) * 1024 + quad * 8);

  for (int it = 1; it < 32; ++it) {
    const int cb = it & 1, pb = cb ^ 1;
    // P(it-1) read — depends only on last iter's write
    bf8_t Pf[4];
#pragma unroll
    for (int qg = 0; qg < 4; ++qg)
      Pf[qg] = *(const bf8_t*)&plds[w][pb][qg * 16 + lane16][quad * 8];
    // prefetch K(it+1), V(it)
    const int kvk = ((it + 1) & 31) * 32;
    const int kvv = it * 32;
    bf8_t K2[2][2], V2[4];
#pragma unroll
    for (int s = 0; s < 2; ++s)
#pragma unroll
      for (int dc = 0; dc < 2; ++dc)
        K2[s][dc] = *(const bf8_t*)(kb + (size_t)(kvk + s * 16 + lane16) * 64 + dc * 32 + quad * 8);
#pragma unroll
    for (int dg = 0; dg < 4; ++dg)
      V2[dg] = *(const bf8_t*)(vb + (size_t)(dg * 16 + lane16) * 1024 + kvv + quad * 8);
    // PV(it-1) — overlaps with S/exp below via pipe separation
#pragma unroll
    for (int dg = 0; dg < 4; ++dg)
#pragma unroll
      for (int qg = 0; qg < 4; ++qg)
        O[dg][qg] = __builtin_amdgcn_mfma_f32_16x16x32_bf16(Vc[dg], Pf[qg], O[dg][qg], 0, 0, 0);
    // S(it) -> exp -> buf cb
    SSTEP(Kc, cb);
    // rotate
#pragma unroll
    for (int s = 0; s < 2; ++s)
#pragma unroll
      for (int dc = 0; dc < 2; ++dc) Kc[s][dc] = K2[s][dc];
#pragma unroll
    for (int dg = 0; dg < 4; ++dg) Vc[dg] = V2[dg];
  }
  {  // epilogue: PV(31), P in buf 1, Vc = V(31)
    bf8_t Pf[4];
#pragma unroll
    for (int qg = 0; qg < 4; ++qg)
      Pf[qg] = *(const bf8_t*)&plds[w][1][qg * 16 + lane16][quad * 8];
#pragma unroll
    for (int dg = 0; dg < 4; ++dg)
#pragma unroll
      for (int qg = 0; qg < 4; ++qg)
        O[dg][qg] = __builtin_amdgcn_mfma_f32_16x16x32_bf16(Vc[dg], Pf[qg], O[dg][qg], 0, 0, 0);
  }

  float rden[4];
#pragma unroll
  for (int qg = 0; qg < 4; ++qg) {
    float d = den[qg];
    d += __shfl_xor(d, 16);
    d += __shfl_xor(d, 32);
    rden[qg] = 1.f / d;
  }

#pragma unroll
  for (int dg = 0; dg < 4; ++dg)
#pragma unroll
    for (int qg = 0; qg < 4; ++qg) {
      const int c0 = h * 64 + dg * 16 + quad * 4;
      const int n = q0 + qg * 16 + lane16;
      uint2 p;
      p.x = pk_rnd(O[dg][qg][0] * rden[qg], O[dg][qg][1] * rden[qg]);
      p.y = pk_rnd(O[dg][qg][2] * rden[qg], O[dg][qg][3] * rden[qg]);
      *(uint2*)(aoT + ((size_t)b * 4096 + n) * 256 + c0) = p;
    }
#undef SSTEP
}

// ---------------- WO gemm (MFMA, K-prefetch) + residual ----------------
__global__ __launch_bounds__(256) void k_gemm_wo(const unsigned short* __restrict__ wob,
                                                 const unsigned short* __restrict__ aoT,
                                                 const float* __restrict__ x,
                                                 const float* __restrict__ gamma,
                                                 float* __restrict__ outp) {
  const int t = threadIdx.x;
  const int w = t >> 6, l = t & 63, lane16 = l & 15, quad = l >> 4;
  const int n0 = blockIdx.x * 64, b = blockIdx.y;
  const unsigned short* Abase = wob + (size_t)(w * 64 + lane16) * 256 + quad * 8;
  const unsigned short* Bbase = aoT + ((size_t)b * 4096 + n0 + lane16) * 256 + quad * 8;
  f4_t acc[4][4];
#pragma unroll
  for (int i = 0; i < 4; ++i)
#pragma unroll
    for (int j = 0; j < 4; ++j) acc[i][j] = (f4_t){0.f, 0.f, 0.f, 0.f};
  bf8_t Ac[4], Bc[4];
#pragma unroll
  for (int og = 0; og < 4; ++og) Ac[og] = *(const bf8_t*)(Abase + (size_t)og * 16 * 256);
#pragma unroll
  for (int ng = 0; ng < 4; ++ng) Bc[ng] = *(const bf8_t*)(Bbase + (size_t)ng * 16 * 256);
  for (int kc = 0; kc < 256; kc += 32) {
    const int kn = (kc + 32) & 255;
    bf8_t An[4], Bn[4];
#pragma unroll
    for (int og = 0; og < 4; ++og) An[og] = *(const bf8_t*)(Abase + (size_t)og * 16 * 256 + kn);
#pragma unroll
    for (int ng = 0; ng < 4; ++ng) Bn[ng] = *(const bf8_t*)(Bbase + (size_t)ng * 16 * 256 + kn);
#pragma unroll
    for (int og = 0; og < 4; ++og)
#pragma unroll
      for (int ng = 0; ng < 4; ++ng)
        acc[og][ng] = __builtin_amdgcn_mfma_f32_16x16x32_bf16(Ac[og], Bc[ng], acc[og][ng], 0, 0, 0);
#pragma unroll
    for (int og = 0; og < 4; ++og) Ac[og] = An[og];
#pragma unroll
    for (int ng = 0; ng < 4; ++ng) Bc[ng] = Bn[ng];
  }
#pragma unroll
  for (int og = 0; og < 4; ++og) {
    float4 g4 = *(const float4*)&gamma[w * 64 + og * 16 + quad * 4];
    const float g[4] = {g4.x, g4.y, g4.z, g4.w};
#pragma unroll
    for (int ng = 0; ng < 4; ++ng) {
      const int n = n0 + ng * 16 + lane16;
#pragma unroll
      for (int r = 0; r < 4; ++r) {
        const int o = w * 64 + og * 16 + quad * 4 + r;
        const size_t ix = ((size_t)(b * 256 + o)) * 4096 + n;
        outp[ix] = x[ix] + g[r] * acc[og][ng][r];
      }
    }
  }
}

extern "C" void kernel_launch(void* const* d_in, const int* in_sizes, int n_in,
                              void* d_out, int out_size, void* d_ws, size_t ws_size,
                              hipStream_t stream) {
  const float* x     = (const float*)d_in[0];
  const float* gnw   = (const float*)d_in[1];
  const float* gnb   = (const float*)d_in[2];
  const float* wq    = (const float*)d_in[3];
  const float* wk    = (const float*)d_in[4];
  const float* wv    = (const float*)d_in[5];
  const float* wo    = (const float*)d_in[6];
  const float* gamma = (const float*)d_in[7];
  float* out = (float*)d_out;
  float* ws  = (float*)d_ws;
  unsigned short* xnT  = (unsigned short*)(ws + WS_XNT);
  unsigned short* xdsT = (unsigned short*)(ws + WS_XDS);
  unsigned short* qbf  = (unsigned short*)(ws + WS_Q);
  unsigned short* kbf  = (unsigned short*)(ws + WS_K);
  unsigned short* vtbf = (unsigned short*)(ws + WS_V);
  unsigned short* aoT  = (unsigned short*)(ws + WS_AOT);
  unsigned short* wqb  = (unsigned short*)(ws + WS_WQB);
  unsigned short* wkvb = (unsigned short*)(ws + WS_WKV);
  unsigned short* wob  = (unsigned short*)(ws + WS_WOB);

  hipMemsetAsync(ws, 0, 256, stream);
  k_prep_stats<<<1152, 256, 0, stream>>>(x, wq, wk, wv, wo, ws + WS_STATS, wqb, wkvb, wob);
  k_xnt<<<dim3(32, 4, 8), 256, 0, stream>>>(x, gnw, gnb, ws + WS_STATS, xnT, xdsT);
  k_gemm_q<<<dim3(64, 8), 256, 0, stream>>>(wqb, xnT, qbf);
  k_gemm_kv<<<dim3(16, 8), 256, 0, stream>>>(wkvb, xdsT, kbf, vtbf);
  k_attn_mfma<<<dim3(32, 4, 8), 128, 0, stream>>>(qbf, kbf, vtbf, aoT);
  k_gemm_wo<<<dim3(64, 8), 256, 0, stream>>>(wob, aoT, x, gamma, out);
}

// Round 7
// 215.122 us; speedup vs baseline: 1.3997x; 1.0816x over previous
//
#include <hip/hip_runtime.h>

// MobileMQA: B=8, C=256, H=W=64, NUM_HEADS=4, hd=64, ds=2
// R7: mega-fusion — one block per (b, 64-n-tile); wave = head.
//     Phase1 Q-proj (LDS restage) -> Phase2 pipelined attention -> Phase3 WO+residual
//     from shared LDS ao tile. qbf/aoT buffers and their kernels deleted.

#define CNT_INV (1.0f/1048576.0f)
#define EPSV 1e-5f
#define QSCALE 0.18033688f   // 0.125 * log2(e): folded into Q; exp becomes v_exp_f32(S)

// workspace layout (float offsets)
#define WS_STATS 0                    // 64
#define WS_XNT   64                   // bf16 xnT [b][n][c]  = 4,194,304 f
#define WS_XDS   4194368              // bf16 xdsT [b][m][c] = 1,048,576 f
#define WS_K     5242944              // bf16 k   [b][m][d]  = 262,144 f
#define WS_V     5505088              // bf16 vT  [b][d][m]  = 262,144 f
#define WS_WQB   5767232              // bf16 wq  [o][c]     = 32,768 f
#define WS_WKV   5800000              // bf16 [wk;wv]        = 16,384 f
#define WS_WOB   5816384              // bf16 wo  [o][c]     = 32,768 f

typedef __attribute__((ext_vector_type(8))) short bf8_t;   // 8 bf16 MFMA A/B frag
typedef __attribute__((ext_vector_type(4))) float f4_t;    // MFMA C/D frag

static __device__ __forceinline__ unsigned fbits(float f) {
  union { float f; unsigned u; } v; v.f = f; return v.u;
}
static __device__ __forceinline__ unsigned short f2bf(float f) {  // RNE
  unsigned u = fbits(f);
  return (unsigned short)((u + 0x7fffu + ((u >> 16) & 1u)) >> 16);
}
static __device__ __forceinline__ unsigned pk_rnd(float a, float b) {
  return __builtin_amdgcn_perm(fbits(b) + 0x8000u, fbits(a) + 0x8000u, 0x07060302u);
}
static __device__ __forceinline__ unsigned pk_tr(float a, float b) {
  return __builtin_amdgcn_perm(fbits(b), fbits(a), 0x07060302u);
}
static __device__ __forceinline__ float bf2f(unsigned short h) {
  union { unsigned u; float f; } v; v.u = ((unsigned)h) << 16; return v.f;
}
static __device__ __forceinline__ float fexp2(float x) {   // 2^x, raw v_exp_f32
  float r; asm("v_exp_f32 %0, %1" : "=v"(r) : "v"(x)); return r;
}

// ---------------- merged: weight prep (blocks >= 512) + stats (blocks < 512) ----------------
__global__ __launch_bounds__(256) void k_prep_stats(const float* __restrict__ x,
                                                    const float* __restrict__ wq,
                                                    const float* __restrict__ wk,
                                                    const float* __restrict__ wv,
                                                    const float* __restrict__ wo,
                                                    float* __restrict__ stats,
                                                    unsigned short* __restrict__ wqb,
                                                    unsigned short* __restrict__ wkvb,
                                                    unsigned short* __restrict__ wob) {
  const int blk = blockIdx.x;
  const int t = threadIdx.x;
  if (blk < 512) {
    const int b = blk >> 6;
    const int chunk = blk & 63;
    const float4* xb = (const float4*)(x + (size_t)b * 1048576 + (size_t)chunk * 16384);
    float s = 0.f, s2 = 0.f;
#pragma unroll
    for (int it = 0; it < 16; ++it) {
      float4 v = xb[it * 256 + t];
      s  += v.x + v.y + v.z + v.w;
      s2 += v.x * v.x + v.y * v.y + v.z * v.z + v.w * v.w;
    }
#pragma unroll
    for (int o = 32; o > 0; o >>= 1) {
      s  += __shfl_down(s, o);
      s2 += __shfl_down(s2, o);
    }
    __shared__ float red[8];
    const int wid = t >> 6;
    if ((t & 63) == 0) { red[wid] = s; red[4 + wid] = s2; }
    __syncthreads();
    if (t == 0) {
      atomicAdd(&stats[b * 2 + 0], red[0] + red[1] + red[2] + red[3]);
      atomicAdd(&stats[b * 2 + 1], red[4] + red[5] + red[6] + red[7]);
    }
  } else {
    const int idx = (blk - 512) * 256 + t;
    if (idx < 65536) wqb[idx] = f2bf(wq[idx]);
    else if (idx < 81920) wkvb[idx - 65536] = f2bf(wk[idx - 65536]);
    else if (idx < 98304) wkvb[idx - 65536] = f2bf(wv[idx - 81920]);
    else if (idx < 163840) wob[idx - 98304] = f2bf(wo[idx - 98304]);
  }
}

// ---------------- normalize + transpose + fused 2x2 pool ----------------
__global__ __launch_bounds__(256) void k_xnt(const float* __restrict__ x,
                                             const float* __restrict__ gnw,
                                             const float* __restrict__ gnb,
                                             const float* __restrict__ stats,
                                             unsigned short* __restrict__ xnT,
                                             unsigned short* __restrict__ xdsT) {
  __shared__ unsigned short T[128][72];   // [n_local][c_local]
  const int t = threadIdx.x;
  const int b = blockIdx.z, c0 = blockIdx.y * 64, hp = blockIdx.x;
  const int n0 = hp * 128;
  const float mu = stats[b * 2 + 0] * CNT_INV;
  const float rstd = rsqrtf(stats[b * 2 + 1] * CNT_INV - mu * mu + EPSV);
  const int n4 = (t & 31) * 4, cl = t >> 5;
#pragma unroll
  for (int p = 0; p < 8; ++p) {
    const int c = c0 + p * 8 + cl;
    const float gw = gnw[c] * rstd;
    const float gb = gnb[c] - mu * rstd * gnw[c];
    float4 v = *(const float4*)&x[(size_t)(b * 256 + c) * 4096 + n0 + n4];
    T[n4 + 0][p * 8 + cl] = f2bf(v.x * gw + gb);
    T[n4 + 1][p * 8 + cl] = f2bf(v.y * gw + gb);
    T[n4 + 2][p * 8 + cl] = f2bf(v.z * gw + gb);
    T[n4 + 3][p * 8 + cl] = f2bf(v.w * gw + gb);
  }
  __syncthreads();
  {  // write xnT: 128 rows x 64 c
    const int r = t >> 1, ch = (t & 1) * 32;
    unsigned short* dst = xnT + ((size_t)b * 4096 + n0 + r) * 256 + c0 + ch;
#pragma unroll
    for (int u = 0; u < 4; ++u)
      *(uint4*)(dst + u * 8) = *(const uint4*)&T[r][ch + u * 8];
  }
  {  // fused pool: 32 m x 64 c
    const int wd = t & 31, c8 = (t >> 5) * 8;
    uint4 u0 = *(const uint4*)&T[2 * wd][c8];
    uint4 u1 = *(const uint4*)&T[2 * wd + 1][c8];
    uint4 u2 = *(const uint4*)&T[64 + 2 * wd][c8];
    uint4 u3 = *(const uint4*)&T[64 + 2 * wd + 1][c8];
    const unsigned* p0 = (const unsigned*)&u0; const unsigned* p1 = (const unsigned*)&u1;
    const unsigned* p2 = (const unsigned*)&u2; const unsigned* p3 = (const unsigned*)&u3;
    unsigned outp[4];
#pragma unroll
    for (int i = 0; i < 4; ++i) {
      float lo = (bf2f((unsigned short)p0[i]) + bf2f((unsigned short)p1[i]) +
                  bf2f((unsigned short)p2[i]) + bf2f((unsigned short)p3[i])) * 0.25f;
      float hi = (bf2f((unsigned short)(p0[i] >> 16)) + bf2f((unsigned short)(p1[i] >> 16)) +
                  bf2f((unsigned short)(p2[i] >> 16)) + bf2f((unsigned short)(p3[i] >> 16))) * 0.25f;
      outp[i] = pk_rnd(lo, hi);
    }
    *(uint4*)(xdsT + ((size_t)b * 1024 + hp * 32 + wd) * 256 + c0 + c8) = *(uint4*)outp;
  }
}

// ---------------- K/V gemm (MFMA, K-prefetch): k[b][m][d], vT[b][d][m] bf16 ----------------
__global__ __launch_bounds__(256) void k_gemm_kv(const unsigned short* __restrict__ wkvb,
                                                 const unsigned short* __restrict__ xdsT,
                                                 unsigned short* __restrict__ kbf,
                                                 unsigned short* __restrict__ vtbf) {
  const int t = threadIdx.x;
  const int w = t >> 6, l = t & 63, lane16 = l & 15, quad = l >> 4;
  const int m0 = blockIdx.x * 64, b = blockIdx.y;
  const unsigned short* Abase = wkvb + (size_t)(w * 32 + lane16) * 256 + quad * 8;
  const unsigned short* Bbase = xdsT + ((size_t)b * 1024 + m0 + lane16) * 256 + quad * 8;
  f4_t acc[2][4];
#pragma unroll
  for (int i = 0; i < 2; ++i)
#pragma unroll
    for (int j = 0; j < 4; ++j) acc[i][j] = (f4_t){0.f, 0.f, 0.f, 0.f};
  bf8_t Ac[2], Bc[4];
#pragma unroll
  for (int og = 0; og < 2; ++og) Ac[og] = *(const bf8_t*)(Abase + (size_t)og * 16 * 256);
#pragma unroll
  for (int mg = 0; mg < 4; ++mg) Bc[mg] = *(const bf8_t*)(Bbase + (size_t)mg * 16 * 256);
  for (int kc = 0; kc < 256; kc += 32) {
    const int kn = (kc + 32) & 255;
    bf8_t An[2], Bn[4];
#pragma unroll
    for (int og = 0; og < 2; ++og) An[og] = *(const bf8_t*)(Abase + (size_t)og * 16 * 256 + kn);
#pragma unroll
    for (int mg = 0; mg < 4; ++mg) Bn[mg] = *(const bf8_t*)(Bbase + (size_t)mg * 16 * 256 + kn);
#pragma unroll
    for (int og = 0; og < 2; ++og)
#pragma unroll
      for (int mg = 0; mg < 4; ++mg)
        acc[og][mg] = __builtin_amdgcn_mfma_f32_16x16x32_bf16(Ac[og], Bc[mg], acc[og][mg], 0, 0, 0);
#pragma unroll
    for (int og = 0; og < 2; ++og) Ac[og] = An[og];
#pragma unroll
    for (int mg = 0; mg < 4; ++mg) Bc[mg] = Bn[mg];
  }
  if (w < 2) {  // K -> kbf[m][d]
#pragma unroll
    for (int og = 0; og < 2; ++og)
#pragma unroll
      for (int mg = 0; mg < 4; ++mg) {
        const int m = m0 + mg * 16 + lane16;
        uint2 p;
        p.x = pk_rnd(acc[og][mg][0], acc[og][mg][1]);
        p.y = pk_rnd(acc[og][mg][2], acc[og][mg][3]);
        *(uint2*)(kbf + (size_t)b * 65536 + (size_t)m * 64 + w * 32 + og * 16 + quad * 4) = p;
      }
  } else {  // V -> vT[d][m]
#pragma unroll
    for (int og = 0; og < 2; ++og)
#pragma unroll
      for (int mg = 0; mg < 4; ++mg) {
        const int m = m0 + mg * 16 + lane16;
        const int d0 = (w - 2) * 32 + og * 16 + quad * 4;
#pragma unroll
        for (int r = 0; r < 4; ++r)
          vtbf[(size_t)b * 65536 + (size_t)(d0 + r) * 1024 + m] = f2bf(acc[og][mg][r]);
      }
  }
}

// ---------------- fused Q-proj + attention + WO + residual ----------------
// block = (b, 64-n tile), wave = head. LDS phases unioned:
//   qst  [4][64][72] u16 (36,864 B)  — Q restage, per wave
//   plds [4][2][64][40] u16 (40,960 B) — P double-buffer, per wave
//   aos  [64][264] u16 (33,792 B)    — block-shared ao tile
__global__ __launch_bounds__(256) void k_fused(const unsigned short* __restrict__ wqb,
                                               const unsigned short* __restrict__ xnT,
                                               const unsigned short* __restrict__ kbf,
                                               const unsigned short* __restrict__ vtbf,
                                               const unsigned short* __restrict__ wob,
                                               const float* __restrict__ x,
                                               const float* __restrict__ gamma,
                                               float* __restrict__ outp) {
  __shared__ __align__(16) unsigned short smem[20480];   // 40,960 B
  const int t = threadIdx.x;
  const int w = t >> 6, l = t & 63, lane16 = l & 15, quad = l >> 4;
  const int n0 = blockIdx.x * 64, b = blockIdx.y;
  const int h = w;
  unsigned short* qst = smem + w * 4608;                               // [64][72]
  unsigned short (*plds)[64][40] = (unsigned short (*)[64][40])(smem + w * 5120);
  unsigned short (*aos)[264] = (unsigned short (*)[264])smem;

  const unsigned short* kb = kbf + (size_t)b * 65536;
  const unsigned short* vb = vtbf + (size_t)b * 65536;

  // ---- Phase 1: Q-proj 64q x 64d for this head, restage via LDS ----
  {
    const unsigned short* Abase = wqb + (size_t)(h * 64 + lane16) * 256 + quad * 8;
    const unsigned short* Bbase = xnT + ((size_t)b * 4096 + n0 + lane16) * 256 + quad * 8;
    f4_t qacc[4][4];
#pragma unroll
    for (int i = 0; i < 4; ++i)
#pragma unroll
      for (int j = 0; j < 4; ++j) qacc[i][j] = (f4_t){0.f, 0.f, 0.f, 0.f};
    for (int kc = 0; kc < 256; kc += 32) {
      bf8_t A[4], Bf[4];
#pragma unroll
      for (int og = 0; og < 4; ++og) A[og] = *(const bf8_t*)(Abase + (size_t)og * 16 * 256 + kc);
#pragma unroll
      for (int ng = 0; ng < 4; ++ng) Bf[ng] = *(const bf8_t*)(Bbase + (size_t)ng * 16 * 256 + kc);
#pragma unroll
      for (int og = 0; og < 4; ++og)
#pragma unroll
        for (int ng = 0; ng < 4; ++ng)
          qacc[og][ng] = __builtin_amdgcn_mfma_f32_16x16x32_bf16(A[og], Bf[ng], qacc[og][ng], 0, 0, 0);
    }
    // C-layout (row d = og*16+quad*4+r, col q = ng*16+lane16) -> qst[q][d]
#pragma unroll
    for (int og = 0; og < 4; ++og)
#pragma unroll
      for (int ng = 0; ng < 4; ++ng) {
        uint2 p;
        p.x = pk_rnd(qacc[og][ng][0] * QSCALE, qacc[og][ng][1] * QSCALE);
        p.y = pk_rnd(qacc[og][ng][2] * QSCALE, qacc[og][ng][3] * QSCALE);
        *(uint2*)&qst[(ng * 16 + lane16) * 72 + og * 16 + quad * 4] = p;
      }
  }
  bf8_t Qf[4][2];
#pragma unroll
  for (int qg = 0; qg < 4; ++qg)
#pragma unroll
    for (int dc = 0; dc < 2; ++dc)
      Qf[qg][dc] = *(const bf8_t*)&qst[(qg * 16 + lane16) * 72 + dc * 32 + quad * 8];
  __syncthreads();   // all waves read Q before plds overwrites qst space

  // ---- Phase 2: pipelined attention (PV lags S by one KV step) ----
  f4_t O[4][4];
#pragma unroll
  for (int dg = 0; dg < 4; ++dg)
#pragma unroll
    for (int qg = 0; qg < 4; ++qg) O[dg][qg] = (f4_t){0.f, 0.f, 0.f, 0.f};
  float den[4] = {0.f, 0.f, 0.f, 0.f};

#define SSTEP(KREG, BUF)                                                      \
  {                                                                           \
    _Pragma("unroll")                                                         \
    for (int qg = 0; qg < 4; ++qg) {                                          \
      _Pragma("unroll")                                                       \
      for (int s = 0; s < 2; ++s) {                                           \
        f4_t S = (f4_t){0.f, 0.f, 0.f, 0.f};                                  \
        S = __builtin_amdgcn_mfma_f32_16x16x32_bf16(KREG[s][0], Qf[qg][0], S, 0, 0, 0); \
        S = __builtin_amdgcn_mfma_f32_16x16x32_bf16(KREG[s][1], Qf[qg][1], S, 0, 0, 0); \
        float e0 = fexp2(S[0]);                                               \
        float e1 = fexp2(S[1]);                                               \
        float e2 = fexp2(S[2]);                                               \
        float e3 = fexp2(S[3]);                                               \
        den[qg] += (e0 + e1) + (e2 + e3);                                     \
        uint2 p; p.x = pk_tr(e0, e1); p.y = pk_tr(e2, e3);                    \
        *(uint2*)&plds[BUF][qg * 16 + lane16][s * 16 + quad * 4] = p;         \
      }                                                                       \
    }                                                                         \
  }

  bf8_t Kc[2][2];
#pragma unroll
  for (int s = 0; s < 2; ++s)
#pragma unroll
    for (int dc = 0; dc < 2; ++dc)
      Kc[s][dc] = *(const bf8_t*)(kb + (size_t)(s * 16 + lane16) * 64 + dc * 32 + quad * 8);
  SSTEP(Kc, 0);

  bf8_t Vc[4];
#pragma unroll
  for (int s = 0; s < 2; ++s)
#pragma unroll
    for (int dc = 0; dc < 2; ++dc)
      Kc[s][dc] = *(const bf8_t*)(kb + (size_t)(32 + s * 16 + lane16) * 64 + dc * 32 + quad * 8);
#pragma unroll
  for (int dg = 0; dg < 4; ++dg)
    Vc[dg] = *(const bf8_t*)(vb + (size_t)(dg * 16 + lane16) * 1024 + quad * 8);

  for (int it = 1; it < 32; ++it) {
    const int cb = it & 1, pb = cb ^ 1;
    bf8_t Pf[4];
#pragma unroll
    for (int qg = 0; qg < 4; ++qg)
      Pf[qg] = *(const bf8_t*)&plds[pb][qg * 16 + lane16][quad * 8];
    const int kvk = ((it + 1) & 31) * 32;
    const int kvv = it * 32;
    bf8_t K2[2][2], V2[4];
#pragma unroll
    for (int s = 0; s < 2; ++s)
#pragma unroll
      for (int dc = 0; dc < 2; ++dc)
        K2[s][dc] = *(const bf8_t*)(kb + (size_t)(kvk + s * 16 + lane16) * 64 + dc * 32 + quad * 8);
#pragma unroll
    for (int dg = 0; dg < 4; ++dg)
      V2[dg] = *(const bf8_t*)(vb + (size_t)(dg * 16 + lane16) * 1024 + kvv + quad * 8);
#pragma unroll
    for (int dg = 0; dg < 4; ++dg)
#pragma unroll
      for (int qg = 0; qg < 4; ++qg)
        O[dg][qg] = __builtin_amdgcn_mfma_f32_16x16x32_bf16(Vc[dg], Pf[qg], O[dg][qg], 0, 0, 0);
    SSTEP(Kc, cb);
#pragma unroll
    for (int s = 0; s < 2; ++s)
#pragma unroll
      for (int dc = 0; dc < 2; ++dc) Kc[s][dc] = K2[s][dc];
#pragma unroll
    for (int dg = 0; dg < 4; ++dg) Vc[dg] = V2[dg];
  }
  {  // epilogue: PV(31), P in buf 1
    bf8_t Pf[4];
#pragma unroll
    for (int qg = 0; qg < 4; ++qg)
      Pf[qg] = *(const bf8_t*)&plds[1][qg * 16 + lane16][quad * 8];
#pragma unroll
    for (int dg = 0; dg < 4; ++dg)
#pragma unroll
      for (int qg = 0; qg < 4; ++qg)
        O[dg][qg] = __builtin_amdgcn_mfma_f32_16x16x32_bf16(Vc[dg], Pf[qg], O[dg][qg], 0, 0, 0);
  }
#undef SSTEP

  float rden[4];
#pragma unroll
  for (int qg = 0; qg < 4; ++qg) {
    float d = den[qg];
    d += __shfl_xor(d, 16);
    d += __shfl_xor(d, 32);
    rden[qg] = 1.f / d;
  }

  __syncthreads();   // all waves done reading plds before aos overwrites
  // ---- write ao tile: rows n, cols c = h*64 + d ----
#pragma unroll
  for (int dg = 0; dg < 4; ++dg)
#pragma unroll
    for (int qg = 0; qg < 4; ++qg) {
      const int c0 = h * 64 + dg * 16 + quad * 4;
      uint2 p;
      p.x = pk_rnd(O[dg][qg][0] * rden[qg], O[dg][qg][1] * rden[qg]);
      p.y = pk_rnd(O[dg][qg][2] * rden[qg], O[dg][qg][3] * rden[qg]);
      *(uint2*)&aos[qg * 16 + lane16][c0] = p;
    }
  __syncthreads();

  // ---- Phase 3: WO gemm from LDS + residual ----
  {
    const unsigned short* Wbase = wob + (size_t)(w * 64 + lane16) * 256 + quad * 8;
    f4_t acc[4][4];
#pragma unroll
    for (int i = 0; i < 4; ++i)
#pragma unroll
      for (int j = 0; j < 4; ++j) acc[i][j] = (f4_t){0.f, 0.f, 0.f, 0.f};
    for (int kc = 0; kc < 256; kc += 32) {
      bf8_t A[4], Bf[4];
#pragma unroll
      for (int og = 0; og < 4; ++og) A[og] = *(const bf8_t*)(Wbase + (size_t)og * 16 * 256 + kc);
#pragma unroll
      for (int ng = 0; ng < 4; ++ng) Bf[ng] = *(const bf8_t*)&aos[ng * 16 + lane16][kc + quad * 8];
#pragma unroll
      for (int og = 0; og < 4; ++og)
#pragma unroll
        for (int ng = 0; ng < 4; ++ng)
          acc[og][ng] = __builtin_amdgcn_mfma_f32_16x16x32_bf16(A[og], Bf[ng], acc[og][ng], 0, 0, 0);
    }
#pragma unroll
    for (int og = 0; og < 4; ++og) {
      float4 g4 = *(const float4*)&gamma[w * 64 + og * 16 + quad * 4];
      const float g[4] = {g4.x, g4.y, g4.z, g4.w};
#pragma unroll
      for (int ng = 0; ng < 4; ++ng) {
        const int n = n0 + ng * 16 + lane16;
#pragma unroll
        for (int r = 0; r < 4; ++r) {
          const int o = w * 64 + og * 16 + quad * 4 + r;
          const size_t ix = ((size_t)(b * 256 + o)) * 4096 + n;
          outp[ix] = x[ix] + g[r] * acc[og][ng][r];
        }
      }
    }
  }
}

extern "C" void kernel_launch(void* const* d_in, const int* in_sizes, int n_in,
                              void* d_out, int out_size, void* d_ws, size_t ws_size,
                              hipStream_t stream) {
  const float* x     = (const float*)d_in[0];
  const float* gnw   = (const float*)d_in[1];
  const float* gnb   = (const float*)d_in[2];
  const float* wq    = (const float*)d_in[3];
  const float* wk    = (const float*)d_in[4];
  const float* wv    = (const float*)d_in[5];
  const float* wo    = (const float*)d_in[6];
  const float* gamma = (const float*)d_in[7];
  float* out = (float*)d_out;
  float* ws  = (float*)d_ws;
  unsigned short* xnT  = (unsigned short*)(ws + WS_XNT);
  unsigned short* xdsT = (unsigned short*)(ws + WS_XDS);
  unsigned short* kbf  = (unsigned short*)(ws + WS_K);
  unsigned short* vtbf = (unsigned short*)(ws + WS_V);
  unsigned short* wqb  = (unsigned short*)(ws + WS_WQB);
  unsigned short* wkvb = (unsigned short*)(ws + WS_WKV);
  unsigned short* wob  = (unsigned short*)(ws + WS_WOB);

  hipMemsetAsync(ws, 0, 256, stream);
  k_prep_stats<<<1152, 256, 0, stream>>>(x, wq, wk, wv, wo, ws + WS_STATS, wqb, wkvb, wob);
  k_xnt<<<dim3(32, 4, 8), 256, 0, stream>>>(x, gnw, gnb, ws + WS_STATS, xnT, xdsT);
  k_gemm_kv<<<dim3(16, 8), 256, 0, stream>>>(wkvb, xdsT, kbf, vtbf);
  k_fused<<<dim3(64, 8), 256, 0, stream>>>(wqb, xnT, kbf, vtbf, wob, x, gamma, out);
}